// Round 1
// baseline (265.427 us; speedup 1.0000x reference)
//
#include <hip/hip_runtime.h>
#include <stdint.h>

// MultiHeadAttention: B=4, C=1024, NH=16, D=64, W=1500 (H=1)
// Pipeline: wconv+xpose -> gemm_qk (Q,K) -> gemm_v (V transposed) -> flash attn -> gemm_out
// All matmul in bf16 MFMA (16x16x32), fp32 accumulate. Threshold 6.1e-3 >> expected ~1e-3 error.

typedef unsigned short u16;
typedef __bf16 bf16x8 __attribute__((ext_vector_type(8)));
typedef float  f32x4  __attribute__((ext_vector_type(4)));
typedef unsigned int __attribute__((address_space(1))) as1_uint;
typedef unsigned int __attribute__((address_space(3))) as3_uint;

__device__ __forceinline__ u16 f2bf(float f) {            // RNE float->bf16
    unsigned u = __float_as_uint(f);
    u += 0x7fffu + ((u >> 16) & 1u);
    return (u16)(u >> 16);
}

__device__ __forceinline__ f32x4 fzero4() { f32x4 z = {0.f, 0.f, 0.f, 0.f}; return z; }

// async global->LDS, 16B per lane. LDS dest must be wave-uniform base + lane*16.
__device__ __forceinline__ void gld16(void* lds, const void* g) {
    __builtin_amdgcn_global_load_lds((const as1_uint*)g, (as3_uint*)lds, 16, 0, 0);
}

// ---------------- prep: weights fp32 -> bf16 (4 x 1M elems) ----------------
__global__ void wconv_k(const float* __restrict__ wq, const float* __restrict__ wk,
                        const float* __restrict__ wv, const float* __restrict__ wo,
                        u16* __restrict__ wb) {
    unsigned idx = blockIdx.x * 256u + threadIdx.x;   // 2^20 threads, 4 elems each
    unsigned m = idx >> 18, r = idx & 0x3ffffu;
    const float* s = (m == 0) ? wq : (m == 1) ? wk : (m == 2) ? wv : wo;
    float4 v = ((const float4*)s)[r];
    uint2 o;
    o.x = (unsigned)f2bf(v.x) | ((unsigned)f2bf(v.y) << 16);
    o.y = (unsigned)f2bf(v.z) | ((unsigned)f2bf(v.w) << 16);
    ((uint2*)(wb + (m << 20)))[r] = o;
}

// ---------------- prep: x [b][c][w] fp32 -> xb [b*w][c] bf16 (LDS transpose) ----------------
__global__ void xpose_k(const float* __restrict__ x, u16* __restrict__ xb) {
    __shared__ float tile[64][65];
    const int b = blockIdx.z;
    const int w0 = blockIdx.x * 64, c0 = blockIdx.y * 64;
    const int tw = threadIdx.x & 63, t4 = threadIdx.x >> 6;
#pragma unroll
    for (int i = 0; i < 16; i++) {
        int c = i * 4 + t4;
        int w = w0 + tw;
        tile[c][tw] = (w < 1500) ? x[((b << 10) + c0 + c) * 1500 + w] : 0.f;
    }
    __syncthreads();
#pragma unroll
    for (int i = 0; i < 16; i++) {
        int wl = i * 4 + t4;
        int w = w0 + wl;
        if (w < 1500) xb[((b * 1500 + w) << 10) + c0 + tw] = f2bf(tile[tw][wl]);
    }
}

// ---------------- shared GEMM core: 128x128 tile, BK=32, NT (both operands [row][k]) ----------------
// A rows clamped to amax, B rows clamped to bmax (duplicate loads; stores masked by caller).
__device__ __forceinline__ void gemm_core(const u16* __restrict__ A, int arow0, int amax,
                                          const u16* __restrict__ Bm, int brow0, int bmax,
                                          f32x4 (&acc)[4][4], unsigned char* lds) {
    const int t = threadIdx.x, l15 = t & 15, lg = (t >> 4) & 3;
    const int wv = t >> 6, wm = wv >> 1, wn = wv & 1;
#pragma unroll
    for (int im = 0; im < 4; im++)
#pragma unroll
        for (int in = 0; in < 4; in++) acc[im][in] = fzero4();

    for (int kt = 0; kt < 32; kt++) {
        const int k0 = kt << 5;
        __syncthreads();
#pragma unroll
        for (int i = 0; i < 2; i++) {
            int xo = (i * 256 + t) << 4;          // byte offset in 8KB half
            int row = xo >> 6, seg = (xo >> 4) & 3;
            int ar = arow0 + row; if (ar > amax) ar = amax;
            int br = brow0 + row; if (br > bmax) br = bmax;
            gld16(lds + xo,        A  + ((long)ar << 10) + k0 + seg * 8);
            gld16(lds + 8192 + xo, Bm + ((long)br << 10) + k0 + seg * 8);
        }
        __syncthreads();
        bf16x8 af[4], bfr[4];
#pragma unroll
        for (int im = 0; im < 4; im++)
            af[im] = *(const bf16x8*)(lds + ((wm * 64 + im * 16 + l15) << 6) + (lg << 4));
#pragma unroll
        for (int in = 0; in < 4; in++)
            bfr[in] = *(const bf16x8*)(lds + 8192 + ((wn * 64 + in * 16 + l15) << 6) + (lg << 4));
#pragma unroll
        for (int im = 0; im < 4; im++)
#pragma unroll
            for (int in = 0; in < 4; in++)
                acc[im][in] = __builtin_amdgcn_mfma_f32_16x16x32_bf16(af[im], bfr[in], acc[im][in], 0, 0, 0);
    }
}

// ---------------- Q,K projections: M=tokens(6000), N=channels(1024) ----------------
// out layout: [b][h][w][64] so attn loads contiguous bf16x8 fragments.
__global__ __launch_bounds__(256) void gemm_qk_k(const u16* __restrict__ xb, const u16* __restrict__ wb,
                                                 const float* __restrict__ bq,
                                                 u16* __restrict__ Q, u16* __restrict__ K) {
    __shared__ __attribute__((aligned(16))) unsigned char lds[16384];
    const int z = blockIdx.z;
    f32x4 acc[4][4];
    gemm_core(xb, blockIdx.x * 128, 5999, wb + (z << 20), blockIdx.y * 128, 1023, acc, lds);

    const int t = threadIdx.x, l15 = t & 15, lg = (t >> 4) & 3;
    const int wv = t >> 6, wm = wv >> 1, wn = wv & 1;
    const int m0 = blockIdx.x * 128 + wm * 64;
    const int n0 = blockIdx.y * 128 + wn * 64;
    u16* dst = z ? K : Q;
    const float* bias = z ? nullptr : bq;
#pragma unroll
    for (int im = 0; im < 4; im++) {
#pragma unroll
        for (int r = 0; r < 4; r++) {
            int tok = m0 + im * 16 + lg * 4 + r;
            if (tok < 6000) {
                int b = tok / 1500, w = tok - b * 1500;
#pragma unroll
                for (int in = 0; in < 4; in++) {
                    int o = n0 + in * 16 + l15;
                    float v = acc[im][in][r] + (bias ? bias[o] : 0.f);
                    dst[((((b << 4) + (o >> 6)) * 1500 + w) << 6) + (o & 63)] = f2bf(v);
                }
            }
        }
    }
}

// ---------------- V projection: M=channels, N=tokens (per batch) -> Vt[b][c][w], stride 1504 ----------------
__global__ __launch_bounds__(256) void gemm_v_k(const u16* __restrict__ xb, const u16* __restrict__ wb,
                                                const float* __restrict__ bv, u16* __restrict__ Vt) {
    __shared__ __attribute__((aligned(16))) unsigned char lds[16384];
    const int b = blockIdx.z;
    f32x4 acc[4][4];
    gemm_core(wb + (2u << 20), blockIdx.x * 128, 1023, xb + b * 1500 * 1024, blockIdx.y * 128, 1499, acc, lds);
    const int t = threadIdx.x, l15 = t & 15, lg = (t >> 4) & 3;
    const int wv = t >> 6, wm = wv >> 1, wn = wv & 1;
    const int m0 = blockIdx.x * 128 + wm * 64;
    const int n0 = blockIdx.y * 128 + wn * 64;
#pragma unroll
    for (int im = 0; im < 4; im++) {
#pragma unroll
        for (int r = 0; r < 4; r++) {
            int o = m0 + im * 16 + lg * 4 + r;
            float bi = bv[o];
#pragma unroll
            for (int in = 0; in < 4; in++) {
                int w = n0 + in * 16 + l15;
                if (w < 1500) Vt[((b << 10) + o) * 1504 + w] = f2bf(acc[im][in][r] + bi);
            }
        }
    }
}

// ---------------- output projection: M=channels, N=tokens (per batch) -> out[b][o][w] fp32 ----------------
__global__ __launch_bounds__(256) void gemm_out_k(const u16* __restrict__ Ow, const u16* __restrict__ wb,
                                                  const float* __restrict__ bo, float* __restrict__ out) {
    __shared__ __attribute__((aligned(16))) unsigned char lds[16384];
    const int b = blockIdx.z;
    f32x4 acc[4][4];
    gemm_core(wb + (3u << 20), blockIdx.x * 128, 1023, Ow + b * 1500 * 1024, blockIdx.y * 128, 1499, acc, lds);
    const int t = threadIdx.x, l15 = t & 15, lg = (t >> 4) & 3;
    const int wv = t >> 6, wm = wv >> 1, wn = wv & 1;
    const int m0 = blockIdx.x * 128 + wm * 64;
    const int n0 = blockIdx.y * 128 + wn * 64;
#pragma unroll
    for (int im = 0; im < 4; im++) {
#pragma unroll
        for (int r = 0; r < 4; r++) {
            int o = m0 + im * 16 + lg * 4 + r;
            float bi = bo[o];
#pragma unroll
            for (int in = 0; in < 4; in++) {
                int w = n0 + in * 16 + l15;
                if (w < 1500) out[(long)((b << 10) + o) * 1500 + w] = acc[im][in][r] + bi;
            }
        }
    }
}

// ---------------- flash attention: block = (b,h) x 64-query tile, 4 waves x 16 queries ----------------
// K_lds/Vt_lds [64][64] bf16 linear (global_load_lds), XOR-swizzled via pre-swizzled global source.
// P (softmax probs) round-trips through padded LDS [64][72] to feed the PV A-operand.
__global__ __launch_bounds__(256) void attn_k(const u16* __restrict__ Q, const u16* __restrict__ K,
                                              const u16* __restrict__ Vt, u16* __restrict__ O) {
    __shared__ __attribute__((aligned(16))) unsigned char lds[16384 + 9216];
    u16* Plds = (u16*)(lds + 16384);

    const int qt = blockIdx.x, bh = blockIdx.y;
    const int b = bh >> 4, h = bh & 15;
    const int t = threadIdx.x, wv = t >> 6, l = t & 63, l15 = l & 15, lg = l >> 4;

    // Q fragments (A-operand): wave's 16 queries = wv*16 + l15
    int q_a = qt * 64 + wv * 16 + l15; if (q_a > 1499) q_a = 1499;
    const u16* qrow = Q + (((long)bh * 1500 + q_a) << 6);
    bf16x8 qa0 = *(const bf16x8*)(qrow + (lg << 3));
    bf16x8 qa1 = *(const bf16x8*)(qrow + 32 + (lg << 3));

    const u16* Kbh = K + (((long)bh * 1500) << 6);
    const u16* Vtb = Vt + (long)((b << 10) + (h << 6)) * 1504;

    f32x4 o_acc[4];
    float m_run[4], l_run[4];
#pragma unroll
    for (int r = 0; r < 4; r++) { o_acc[r] = fzero4(); m_run[r] = -1e30f; l_run[r] = 0.f; }
    const float SC = 0.18033688011112042f;   // d^-0.5 * log2(e) = 0.125*1.4426950408889634

    for (int kv = 0; kv < 24; kv++) {
        const int kv0 = kv << 6;
        __syncthreads();   // prior tile fully consumed
#pragma unroll
        for (int i = 0; i < 2; i++) {
            int xo = (i * 256 + t) << 4;                 // LDS byte, linear
            int row = xo >> 7, seg = (xo >> 4) & 7;
            int sw = (seg ^ (row & 7)) << 3;             // inverse-swizzled source column (elems)
            int kg = kv0 + row; if (kg > 1499) kg = 1499;        // K: row = key (masked later)
            gld16(lds + xo, Kbh + (kg << 6) + sw);
            int st = kv0 + sw; if (st > 1496) st = 1496;         // Vt: row = d, clamp keeps 16B in-bounds
            gld16(lds + 8192 + xo, Vtb + row * 1504 + st);
        }
        __syncthreads();

        // S = Q K^T (per wave: 16 q x 64 keys)
        f32x4 s[4];
#pragma unroll
        for (int nf = 0; nf < 4; nf++) {
            s[nf] = fzero4();
            int key = nf * 16 + l15;
            const unsigned char* kp = lds + (key << 7);
            bf16x8 kb0 = *(const bf16x8*)(kp + ((lg ^ (key & 7)) << 4));
            bf16x8 kb1 = *(const bf16x8*)(kp + (((4 + lg) ^ (key & 7)) << 4));
            s[nf] = __builtin_amdgcn_mfma_f32_16x16x32_bf16(qa0, kb0, s[nf], 0, 0, 0);
            s[nf] = __builtin_amdgcn_mfma_f32_16x16x32_bf16(qa1, kb1, s[nf], 0, 0, 0);
        }

        // online softmax over keys (cols = lane&15 across 16 lanes, 4 frags in-lane)
        float mx[4], p[4][4], psum[4];
#pragma unroll
        for (int r = 0; r < 4; r++) mx[r] = -3.0e38f;
#pragma unroll
        for (int nf = 0; nf < 4; nf++) {
            bool valid = (kv0 + nf * 16 + l15) < 1500;
#pragma unroll
            for (int r = 0; r < 4; r++) {
                float v2 = valid ? s[nf][r] * SC : -1e30f;
                s[nf][r] = v2;
                mx[r] = fmaxf(mx[r], v2);
            }
        }
#pragma unroll
        for (int d = 1; d < 16; d <<= 1)
#pragma unroll
            for (int r = 0; r < 4; r++) mx[r] = fmaxf(mx[r], __shfl_xor(mx[r], d));
        float mnew[4], sc[4];
#pragma unroll
        for (int r = 0; r < 4; r++) {
            mnew[r] = fmaxf(m_run[r], mx[r]);
            sc[r] = exp2f(m_run[r] - mnew[r]);
            psum[r] = 0.f;
        }
#pragma unroll
        for (int nf = 0; nf < 4; nf++)
#pragma unroll
            for (int r = 0; r < 4; r++) {
                float pv = exp2f(s[nf][r] - mnew[r]);   // invalid keys: exp2(-1e30) = 0
                p[nf][r] = pv;
                psum[r] += pv;
            }
#pragma unroll
        for (int d = 1; d < 16; d <<= 1)
#pragma unroll
            for (int r = 0; r < 4; r++) psum[r] += __shfl_xor(psum[r], d);
#pragma unroll
        for (int r = 0; r < 4; r++) {
            l_run[r] = l_run[r] * sc[r] + psum[r];
            m_run[r] = mnew[r];
        }
        // P -> LDS (bf16), rescale O
#pragma unroll
        for (int nf = 0; nf < 4; nf++)
#pragma unroll
            for (int r = 0; r < 4; r++)
                Plds[(wv * 16 + lg * 4 + r) * 72 + nf * 16 + l15] = f2bf(p[nf][r]);
#pragma unroll
        for (int nf = 0; nf < 4; nf++) {
            f32x4 oa = o_acc[nf];
#pragma unroll
            for (int r = 0; r < 4; r++) oa[r] *= sc[r];
            o_acc[nf] = oa;
        }
        __syncthreads();   // P visible (wave-local, but be safe)

        // O += P V  (B-operand: 8 consecutive keys at fixed d from Vt_lds, swizzled)
#pragma unroll
        for (int kk = 0; kk < 2; kk++) {
            bf16x8 pa = *(const bf16x8*)(Plds + (wv * 16 + l15) * 72 + (kk << 5) + (lg << 3));
#pragma unroll
            for (int nf = 0; nf < 4; nf++) {
                int drow = nf * 16 + l15;
                bf16x8 vb = *(const bf16x8*)(lds + 8192 + (drow << 7) + ((((kk << 2) + lg) ^ (drow & 7)) << 4));
                o_acc[nf] = __builtin_amdgcn_mfma_f32_16x16x32_bf16(pa, vb, o_acc[nf], 0, 0, 0);
            }
        }
    }

    // epilogue: O[q][d] / l -> O_ws[t][c] bf16
#pragma unroll
    for (int r = 0; r < 4; r++) {
        int q = qt * 64 + wv * 16 + lg * 4 + r;
        if (q < 1500) {
            float inv = 1.f / l_run[r];
            u16* dst = O + ((long)(b * 1500 + q) << 10) + (h << 6);
#pragma unroll
            for (int nf = 0; nf < 4; nf++)
                dst[nf * 16 + l15] = f2bf(o_acc[nf][r] * inv);
        }
    }
}

// ---------------- launch ----------------
extern "C" void kernel_launch(void* const* d_in, const int* in_sizes, int n_in,
                              void* d_out, int out_size, void* d_ws, size_t ws_size,
                              hipStream_t stream) {
    const float* x  = (const float*)d_in[0];
    const float* Wq = (const float*)d_in[1];
    const float* bq = (const float*)d_in[2];
    const float* Wk = (const float*)d_in[3];
    const float* Wv = (const float*)d_in[4];
    const float* bv = (const float*)d_in[5];
    const float* Wo = (const float*)d_in[6];
    const float* bo = (const float*)d_in[7];
    float* out = (float*)d_out;

    // workspace layout (bytes):
    //   xb [6000][1024] bf16 : 12,288,000   (reused as O_ws after gemm_v consumes it)
    //   wb [4][2^20]    bf16 :  8,388,608
    //   Q  [4][16][1500][64] : 12,288,000
    //   K                    : 12,288,000
    //   Vt [4][1024][1504]   : 12,320,768
    const size_t NEED = 57573376;
    if (ws_size < NEED) return;   // visible failure if workspace too small

    unsigned char* ws = (unsigned char*)d_ws;
    u16* xb = (u16*)(ws);
    u16* wb = (u16*)(ws + 12288000);
    u16* Qw = (u16*)(ws + 20676608);
    u16* Kw = (u16*)(ws + 32964608);
    u16* Vt = (u16*)(ws + 45252608);

    wconv_k<<<dim3(4096), dim3(256), 0, stream>>>(Wq, Wk, Wv, Wo, wb);
    xpose_k<<<dim3(24, 16, 4), dim3(256), 0, stream>>>(x, xb);
    gemm_qk_k<<<dim3(47, 8, 2), dim3(256), 0, stream>>>(xb, wb, bq, Qw, Kw);
    gemm_v_k<<<dim3(8, 12, 4), dim3(256), 0, stream>>>(xb, wb, bv, Vt);
    attn_k<<<dim3(24, 64), dim3(256), 0, stream>>>(Qw, Kw, Vt, xb /* -> O_ws */);
    gemm_out_k<<<dim3(8, 12, 4), dim3(256), 0, stream>>>(xb, wb, bo, out);
}

// Round 2
// 196.412 us; speedup vs baseline: 1.3514x; 1.3514x over previous
//
#include <hip/hip_runtime.h>
#include <stdint.h>

// MultiHeadAttention: B=4, C=1024, NH=16, D=64, W=1500 (H=1)
// Pipeline: wconv+xpose -> gemm_qk (Q,K) -> gemm_v (V transposed) -> flash attn -> gemm_out
// Attn v2: swapped QK^T (S^T=mfma(K,Q)) -> in-lane softmax, b64 P writes, K/V LDS
// double-buffer with 1 barrier/tile, defer-max rescale skip. 8 waves/block, QBLK=128.

typedef unsigned short u16;
typedef __bf16 bf16x8 __attribute__((ext_vector_type(8)));
typedef __bf16 bf16x4 __attribute__((ext_vector_type(4)));
typedef float  f32x4  __attribute__((ext_vector_type(4)));
typedef unsigned int __attribute__((address_space(1))) as1_uint;
typedef unsigned int __attribute__((address_space(3))) as3_uint;

__device__ __forceinline__ u16 f2bf(float f) {            // RNE float->bf16
    unsigned u = __float_as_uint(f);
    u += 0x7fffu + ((u >> 16) & 1u);
    return (u16)(u >> 16);
}

__device__ __forceinline__ f32x4 fzero4() { f32x4 z = {0.f, 0.f, 0.f, 0.f}; return z; }

// async global->LDS, 16B per lane. LDS dest must be wave-uniform base + lane*16.
__device__ __forceinline__ void gld16(void* lds, const void* g) {
    __builtin_amdgcn_global_load_lds((const as1_uint*)g, (as3_uint*)lds, 16, 0, 0);
}

// ---------------- prep: weights fp32 -> bf16 (4 x 1M elems) ----------------
__global__ void wconv_k(const float* __restrict__ wq, const float* __restrict__ wk,
                        const float* __restrict__ wv, const float* __restrict__ wo,
                        u16* __restrict__ wb) {
    unsigned idx = blockIdx.x * 256u + threadIdx.x;   // 2^20 threads, 4 elems each
    unsigned m = idx >> 18, r = idx & 0x3ffffu;
    const float* s = (m == 0) ? wq : (m == 1) ? wk : (m == 2) ? wv : wo;
    float4 v = ((const float4*)s)[r];
    uint2 o;
    o.x = (unsigned)f2bf(v.x) | ((unsigned)f2bf(v.y) << 16);
    o.y = (unsigned)f2bf(v.z) | ((unsigned)f2bf(v.w) << 16);
    ((uint2*)(wb + (m << 20)))[r] = o;
}

// ---------------- prep: x [b][c][w] fp32 -> xb [b*w][c] bf16 (LDS transpose) ----------------
__global__ void xpose_k(const float* __restrict__ x, u16* __restrict__ xb) {
    __shared__ float tile[64][65];
    const int b = blockIdx.z;
    const int w0 = blockIdx.x * 64, c0 = blockIdx.y * 64;
    const int tw = threadIdx.x & 63, t4 = threadIdx.x >> 6;
#pragma unroll
    for (int i = 0; i < 16; i++) {
        int c = i * 4 + t4;
        int w = w0 + tw;
        tile[c][tw] = (w < 1500) ? x[((b << 10) + c0 + c) * 1500 + w] : 0.f;
    }
    __syncthreads();
#pragma unroll
    for (int i = 0; i < 16; i++) {
        int wl = i * 4 + t4;
        int w = w0 + wl;
        if (w < 1500) xb[((b * 1500 + w) << 10) + c0 + tw] = f2bf(tile[tw][wl]);
    }
}

// ---------------- shared GEMM core: 128x128 tile, BK=32, NT (both operands [row][k]) ----------------
__device__ __forceinline__ void gemm_core(const u16* __restrict__ A, int arow0, int amax,
                                          const u16* __restrict__ Bm, int brow0, int bmax,
                                          f32x4 (&acc)[4][4], unsigned char* lds) {
    const int t = threadIdx.x, l15 = t & 15, lg = (t >> 4) & 3;
    const int wv = t >> 6, wm = wv >> 1, wn = wv & 1;
#pragma unroll
    for (int im = 0; im < 4; im++)
#pragma unroll
        for (int in = 0; in < 4; in++) acc[im][in] = fzero4();

    for (int kt = 0; kt < 32; kt++) {
        const int k0 = kt << 5;
        __syncthreads();
#pragma unroll
        for (int i = 0; i < 2; i++) {
            int xo = (i * 256 + t) << 4;          // byte offset in 8KB half
            int row = xo >> 6, seg = (xo >> 4) & 3;
            int ar = arow0 + row; if (ar > amax) ar = amax;
            int br = brow0 + row; if (br > bmax) br = bmax;
            gld16(lds + xo,        A  + ((long)ar << 10) + k0 + seg * 8);
            gld16(lds + 8192 + xo, Bm + ((long)br << 10) + k0 + seg * 8);
        }
        __syncthreads();
        bf16x8 af[4], bfr[4];
#pragma unroll
        for (int im = 0; im < 4; im++)
            af[im] = *(const bf16x8*)(lds + ((wm * 64 + im * 16 + l15) << 6) + (lg << 4));
#pragma unroll
        for (int in = 0; in < 4; in++)
            bfr[in] = *(const bf16x8*)(lds + 8192 + ((wn * 64 + in * 16 + l15) << 6) + (lg << 4));
#pragma unroll
        for (int im = 0; im < 4; im++)
#pragma unroll
            for (int in = 0; in < 4; in++)
                acc[im][in] = __builtin_amdgcn_mfma_f32_16x16x32_bf16(af[im], bfr[in], acc[im][in], 0, 0, 0);
    }
}

// ---------------- Q,K projections: M=tokens(6000), N=channels(1024) ----------------
__global__ __launch_bounds__(256) void gemm_qk_k(const u16* __restrict__ xb, const u16* __restrict__ wb,
                                                 const float* __restrict__ bq,
                                                 u16* __restrict__ Q, u16* __restrict__ K) {
    __shared__ __attribute__((aligned(16))) unsigned char lds[16384];
    const int z = blockIdx.z;
    f32x4 acc[4][4];
    gemm_core(xb, blockIdx.x * 128, 5999, wb + (z << 20), blockIdx.y * 128, 1023, acc, lds);

    const int t = threadIdx.x, l15 = t & 15, lg = (t >> 4) & 3;
    const int wv = t >> 6, wm = wv >> 1, wn = wv & 1;
    const int m0 = blockIdx.x * 128 + wm * 64;
    const int n0 = blockIdx.y * 128 + wn * 64;
    u16* dst = z ? K : Q;
    const float* bias = z ? nullptr : bq;
#pragma unroll
    for (int im = 0; im < 4; im++) {
#pragma unroll
        for (int r = 0; r < 4; r++) {
            int tok = m0 + im * 16 + lg * 4 + r;
            if (tok < 6000) {
                int b = tok / 1500, w = tok - b * 1500;
#pragma unroll
                for (int in = 0; in < 4; in++) {
                    int o = n0 + in * 16 + l15;
                    float v = acc[im][in][r] + (bias ? bias[o] : 0.f);
                    dst[((((b << 4) + (o >> 6)) * 1500 + w) << 6) + (o & 63)] = f2bf(v);
                }
            }
        }
    }
}

// ---------------- V projection: M=channels, N=tokens (per batch) -> Vt[b][c][w], stride 1504 ----------------
__global__ __launch_bounds__(256) void gemm_v_k(const u16* __restrict__ xb, const u16* __restrict__ wb,
                                                const float* __restrict__ bv, u16* __restrict__ Vt) {
    __shared__ __attribute__((aligned(16))) unsigned char lds[16384];
    const int b = blockIdx.z;
    f32x4 acc[4][4];
    gemm_core(wb + (2u << 20), blockIdx.x * 128, 1023, xb + b * 1500 * 1024, blockIdx.y * 128, 1499, acc, lds);
    const int t = threadIdx.x, l15 = t & 15, lg = (t >> 4) & 3;
    const int wv = t >> 6, wm = wv >> 1, wn = wv & 1;
    const int m0 = blockIdx.x * 128 + wm * 64;
    const int n0 = blockIdx.y * 128 + wn * 64;
#pragma unroll
    for (int im = 0; im < 4; im++) {
#pragma unroll
        for (int r = 0; r < 4; r++) {
            int o = m0 + im * 16 + lg * 4 + r;
            float bi = bv[o];
#pragma unroll
            for (int in = 0; in < 4; in++) {
                int w = n0 + in * 16 + l15;
                if (w < 1500)      Vt[((b << 10) + o) * 1504 + w] = f2bf(acc[im][in][r] + bi);
                else if (w < 1504) Vt[((b << 10) + o) * 1504 + w] = 0;   // finite pad for attn tail reads
            }
        }
    }
}

// ---------------- output projection: M=channels, N=tokens (per batch) -> out[b][o][w] fp32 ----------------
__global__ __launch_bounds__(256) void gemm_out_k(const u16* __restrict__ Ow, const u16* __restrict__ wb,
                                                  const float* __restrict__ bo, float* __restrict__ out) {
    __shared__ __attribute__((aligned(16))) unsigned char lds[16384];
    const int b = blockIdx.z;
    f32x4 acc[4][4];
    gemm_core(wb + (3u << 20), blockIdx.x * 128, 1023, Ow + b * 1500 * 1024, blockIdx.y * 128, 1499, acc, lds);
    const int t = threadIdx.x, l15 = t & 15, lg = (t >> 4) & 3;
    const int wv = t >> 6, wm = wv >> 1, wn = wv & 1;
    const int m0 = blockIdx.x * 128 + wm * 64;
    const int n0 = blockIdx.y * 128 + wn * 64;
#pragma unroll
    for (int im = 0; im < 4; im++) {
#pragma unroll
        for (int r = 0; r < 4; r++) {
            int o = m0 + im * 16 + lg * 4 + r;
            float bi = bo[o];
#pragma unroll
            for (int in = 0; in < 4; in++) {
                int w = n0 + in * 16 + l15;
                if (w < 1500) out[(long)((b << 10) + o) * 1500 + w] = acc[im][in][r] + bi;
            }
        }
    }
}

// ---------------- flash attention v2 ----------------
// Block: 512 threads = 8 waves, each wave owns 16 queries (QBLK=128). Grid 12 x 64.
// LDS: K dbuf [2][64][64]bf16 @0 (16KB), V dbuf [2][64][64] @16384 (16KB),
//      P per-wave [16][72]bf16 @32768 (8*2304B). Total 51200B -> 3 blocks/CU.
// Swapped QK^T: s[kt] = S^T, lane holds q=lane&15, keys 16*kt+4*g+r (g=(lane>>4)&3).
__global__ __launch_bounds__(512) void attn_k(const u16* __restrict__ Q, const u16* __restrict__ K,
                                              const u16* __restrict__ Vt, u16* __restrict__ O) {
    __shared__ __attribute__((aligned(16))) unsigned char lds[51200];

    const int qt = blockIdx.x, bh = blockIdx.y;
    const int b = bh >> 4, h = bh & 15;
    const int t = threadIdx.x, wv = t >> 6, l15 = t & 15, g = (t >> 4) & 3;
    const int sk7 = l15 & 7;
    unsigned char* Pw = lds + 32768 + wv * 2304;

    // Q fragments (B-operand): col q = l15, k(d) = 8g..+7 (+32)
    int q_a = qt * 128 + wv * 16 + l15; if (q_a > 1499) q_a = 1499;
    const u16* qrow = Q + (((long)bh * 1500 + q_a) << 6);
    bf16x8 qb0 = *(const bf16x8*)(qrow + (g << 3));
    bf16x8 qb1 = *(const bf16x8*)(qrow + 32 + (g << 3));

    const u16* Kbh = K + (((long)bh * 1500) << 6);
    const u16* Vtb = Vt + (long)((b << 10) + (h << 6)) * 1504;

    // staging: each thread 1x16B for K, 1x16B for V. LDS linear, source pre-swizzled.
    const int srow = t >> 3;                       // 0..63
    const int ssw  = ((t & 7) ^ (srow & 7)) << 3;  // element offset of 8-elem segment
    unsigned char* kdst = lds + (t << 4);
    unsigned char* vdst = lds + 16384 + (t << 4);

    f32x4 o_acc[4];
#pragma unroll
    for (int nf = 0; nf < 4; nf++) o_acc[nf] = fzero4();
    float m_run = -1e30f, l_part = 0.f;
    const float SC = 0.18033688011112042f;   // d^-0.5 * log2(e)

    {   // prologue: stage tile 0 into buf 0
        int kg = srow; // tile 0: kv0=0, always valid
        gld16(kdst, Kbh + ((long)kg << 6) + ssw);
        gld16(vdst, Vtb + (long)srow * 1504 + ssw);
    }
    __syncthreads();

    for (int tile = 0; tile < 24; ++tile) {
        const int cur = tile & 1;
        if (tile < 23) {   // stage next tile into other buffer (overlaps compute)
            int kv0 = (tile + 1) << 6;
            int kg = kv0 + srow; if (kg > 1499) kg = 1499;
            gld16(kdst + ((cur ^ 1) << 13), Kbh + ((long)kg << 6) + ssw);
            int vc = kv0 + ssw; if (vc > 1496) vc = 1496;   // cols 1500..1503 are zero-padded
            gld16(vdst + ((cur ^ 1) << 13), Vtb + (long)srow * 1504 + vc);
        }
        const unsigned char* Kl = lds + (cur << 13);
        const unsigned char* Vl = lds + 16384 + (cur << 13);

        // S^T = K Q^T : s[kt][r] = score(key = 16kt+4g+r, q = l15), raw (unscaled)
        f32x4 s[4];
#pragma unroll
        for (int kt = 0; kt < 4; kt++) {
            const unsigned char* kp = Kl + ((kt * 16 + l15) << 7);
            bf16x8 ka0 = *(const bf16x8*)(kp + ((g ^ sk7) << 4));
            bf16x8 ka1 = *(const bf16x8*)(kp + (((g + 4) ^ sk7) << 4));
            f32x4 z = fzero4();
            z = __builtin_amdgcn_mfma_f32_16x16x32_bf16(ka0, qb0, z, 0, 0, 0);
            z = __builtin_amdgcn_mfma_f32_16x16x32_bf16(ka1, qb1, z, 0, 0, 0);
            s[kt] = z;
        }
        if (tile == 23) {   // mask keys >= 1500 (kv0 = 1472, 28 valid)
#pragma unroll
            for (int kt = 0; kt < 4; kt++)
#pragma unroll
                for (int r = 0; r < 4; r++)
                    if (kt * 16 + g * 4 + r >= 28) s[kt][r] = -1e30f;
        }

        // running max (raw domain); reduce in-lane then across the 4 g-groups
        float mx = fmaxf(fmaxf(fmaxf(s[0][0], s[0][1]), fmaxf(s[0][2], s[0][3])),
                         fmaxf(fmaxf(s[1][0], s[1][1]), fmaxf(s[1][2], s[1][3])));
        float mx2 = fmaxf(fmaxf(fmaxf(s[2][0], s[2][1]), fmaxf(s[2][2], s[2][3])),
                          fmaxf(fmaxf(s[3][0], s[3][1]), fmaxf(s[3][2], s[3][3])));
        mx = fmaxf(mx, mx2);
        mx = fmaxf(mx, __shfl_xor(mx, 16));
        mx = fmaxf(mx, __shfl_xor(mx, 32));

        // defer-max: only rescale when max grew by > 44 raw (2^(44*SC) ~ 2^8 headroom)
        if (!__all(mx <= m_run + 44.f)) {
            float mnew = fmaxf(m_run, mx);
            float sc = exp2f((m_run - mnew) * SC);
            l_part *= sc;
#pragma unroll
            for (int r = 0; r < 4; r++) {
                float sco = __shfl(sc, g * 4 + r);   // sc for o_acc row q = 4g+r
#pragma unroll
                for (int nf = 0; nf < 4; nf++) o_acc[nf][r] *= sco;
            }
            m_run = mnew;
        }

        // P = exp2((s - m)*SC); pack 4 keys -> b64 write into Plds[q][key]
        const float msc = m_run * SC;
        float psum = 0.f;
#pragma unroll
        for (int kt = 0; kt < 4; kt++) {
            float p0 = exp2f(fmaf(s[kt][0], SC, -msc));
            float p1 = exp2f(fmaf(s[kt][1], SC, -msc));
            float p2 = exp2f(fmaf(s[kt][2], SC, -msc));
            float p3 = exp2f(fmaf(s[kt][3], SC, -msc));
            psum += (p0 + p1) + (p2 + p3);
            bf16x4 pk;
            pk[0] = (__bf16)p0; pk[1] = (__bf16)p1; pk[2] = (__bf16)p2; pk[3] = (__bf16)p3;
            *(bf16x4*)(Pw + l15 * 144 + kt * 32 + g * 8) = pk;
        }
        l_part += psum;   // lane-partial (covers this lane's 16 keys); cross-g reduce at end

        // O += P V : A = Plds[q][k] contiguous, B = V_lds[d][key] swizzled
#pragma unroll
        for (int hh = 0; hh < 2; hh++) {
            bf16x8 pa = *(const bf16x8*)(Pw + l15 * 144 + hh * 64 + g * 16);
#pragma unroll
            for (int nf = 0; nf < 4; nf++) {
                const unsigned char* vp = Vl + ((nf * 16 + l15) << 7);
                bf16x8 vb = *(const bf16x8*)(vp + (((g + 4 * hh) ^ sk7) << 4));
                o_acc[nf] = __builtin_amdgcn_mfma_f32_16x16x32_bf16(pa, vb, o_acc[nf], 0, 0, 0);
            }
        }
        __syncthreads();   // next-tile loads landed; everyone done with buf[cur]
    }

    // epilogue: total l across g-groups, normalize, write O[token][c]
    l_part += __shfl_xor(l_part, 16);
    l_part += __shfl_xor(l_part, 32);
    float inv = 1.f / l_part;     // per query q = l15, uniform across g
#pragma unroll
    for (int r = 0; r < 4; r++) {
        float invr = __shfl(inv, g * 4 + r);      // for o_acc row q = 4g+r
        int q = qt * 128 + wv * 16 + g * 4 + r;
        if (q < 1500) {
            u16* dst = O + ((long)(b * 1500 + q) << 10) + (h << 6);
#pragma unroll
            for (int nf = 0; nf < 4; nf++)
                dst[nf * 16 + l15] = f2bf(o_acc[nf][r] * invr);
        }
    }
}

// ---------------- launch ----------------
extern "C" void kernel_launch(void* const* d_in, const int* in_sizes, int n_in,
                              void* d_out, int out_size, void* d_ws, size_t ws_size,
                              hipStream_t stream) {
    const float* x  = (const float*)d_in[0];
    const float* Wq = (const float*)d_in[1];
    const float* bq = (const float*)d_in[2];
    const float* Wk = (const float*)d_in[3];
    const float* Wv = (const float*)d_in[4];
    const float* bv = (const float*)d_in[5];
    const float* Wo = (const float*)d_in[6];
    const float* bo = (const float*)d_in[7];
    float* out = (float*)d_out;

    // workspace layout (bytes):
    //   xb [6000][1024] bf16 : 12,288,000   (reused as O_ws after gemm_v consumes it)
    //   wb [4][2^20]    bf16 :  8,388,608
    //   Q  [4][16][1500][64] : 12,288,000
    //   K                    : 12,288,000
    //   Vt [4][1024][1504]   : 12,320,768
    const size_t NEED = 57573376;
    if (ws_size < NEED) return;   // visible failure if workspace too small

    unsigned char* ws = (unsigned char*)d_ws;
    u16* xb = (u16*)(ws);
    u16* wb = (u16*)(ws + 12288000);
    u16* Qw = (u16*)(ws + 20676608);
    u16* Kw = (u16*)(ws + 32964608);
    u16* Vt = (u16*)(ws + 45252608);

    wconv_k<<<dim3(4096), dim3(256), 0, stream>>>(Wq, Wk, Wv, Wo, wb);
    xpose_k<<<dim3(24, 16, 4), dim3(256), 0, stream>>>(x, xb);
    gemm_qk_k<<<dim3(47, 8, 2), dim3(256), 0, stream>>>(xb, wb, bq, Qw, Kw);
    gemm_v_k<<<dim3(8, 12, 4), dim3(256), 0, stream>>>(xb, wb, bv, Vt);
    attn_k<<<dim3(12, 64), dim3(512), 0, stream>>>(Qw, Kw, Vt, xb /* -> O_ws */);
    gemm_out_k<<<dim3(8, 12, 4), dim3(256), 0, stream>>>(xb, wb, bo, out);
}